// Round 1
// baseline (131.831 us; speedup 1.0000x reference)
//
#include <hip/hip_runtime.h>
#include <hip/hip_bf16.h>

typedef __bf16 bf16_t;
typedef __attribute__((ext_vector_type(8))) __bf16 bf16x8;
typedef __attribute__((ext_vector_type(4))) float f32x4;

#define SEQ    2048
#define DMODEL 1024
#define DPROJ  256
#define NBATCH 4

__device__ __forceinline__ bf16x8 cvt8(const float4& lo, const float4& hi) {
    bf16x8 v;
    v[0] = (bf16_t)lo.x; v[1] = (bf16_t)lo.y; v[2] = (bf16_t)lo.z; v[3] = (bf16_t)lo.w;
    v[4] = (bf16_t)hi.x; v[5] = (bf16_t)hi.y; v[6] = (bf16_t)hi.z; v[7] = (bf16_t)hi.w;
    return v;
}

// ---------------------------------------------------------------------------
// Kernel 1 (R4 known-good, ~23us): H[m,p] = relu(sum_d X[m,d]*W[p,d] + b[p]).
// BM=BN=64, BK=64, grid 512, LDS staging + distance-2 VGPR prefetch.
// UNCHANGED this round — isolate the score-kernel rewrite.
// ---------------------------------------------------------------------------
__global__ __launch_bounds__(256) void proj_kernel(
    const float* __restrict__ X, const float* __restrict__ W,
    const float* __restrict__ bias, bf16_t* __restrict__ H)
{
    __shared__ __align__(16) bf16_t Xs[64 * 64];
    __shared__ __align__(16) bf16_t Ws[64 * 64];

    const int m0 = blockIdx.x * 64;
    const int n0 = blockIdx.y * 64;
    const int tid  = threadIdx.x;
    const int lane = tid & 63;
    const int wave = tid >> 6;
    const int quad = lane >> 4;
    const int l16  = lane & 15;
    const int wm = (wave & 1) * 32;
    const int wn = (wave >> 1) * 32;
    const int swz = l16 & 7;

    int srow[2], scol[2];
    bf16_t* lx[2];
    bf16_t* lw[2];
    #pragma unroll
    for (int r = 0; r < 2; ++r) {
        const int p = r * 256 + tid;
        srow[r] = p >> 3;
        scol[r] = p & 7;
        const int cs = (scol[r] ^ (srow[r] & 7)) * 8;
        lx[r] = Xs + srow[r] * 64 + cs;
        lw[r] = Ws + srow[r] * 64 + cs;
    }

    float4 xr[2][2][2], wr[2][2][2];   // [stage][r][half]

    #pragma unroll
    for (int s = 0; s < 2; ++s) {
        const int k0 = s * 64;
        #pragma unroll
        for (int r = 0; r < 2; ++r) {
            const float* gx = X + (size_t)(m0 + srow[r]) * DMODEL + k0 + scol[r] * 8;
            xr[s][r][0] = *(const float4*)gx;
            xr[s][r][1] = *(const float4*)(gx + 4);
            const float* gw = W + (size_t)(n0 + srow[r]) * DMODEL + k0 + scol[r] * 8;
            wr[s][r][0] = *(const float4*)gw;
            wr[s][r][1] = *(const float4*)(gw + 4);
        }
    }

    f32x4 acc[2][2] = {};

    #pragma unroll
    for (int kt = 0; kt < 16; ++kt) {
        const int s = kt & 1;
        __syncthreads();
        #pragma unroll
        for (int r = 0; r < 2; ++r) {
            *(bf16x8*)lx[r] = cvt8(xr[s][r][0], xr[s][r][1]);
            *(bf16x8*)lw[r] = cvt8(wr[s][r][0], wr[s][r][1]);
        }
        __syncthreads();

        if (kt < 14) {
            const int k0 = (kt + 2) * 64;
            #pragma unroll
            for (int r = 0; r < 2; ++r) {
                const float* gx = X + (size_t)(m0 + srow[r]) * DMODEL + k0 + scol[r] * 8;
                xr[s][r][0] = *(const float4*)gx;
                xr[s][r][1] = *(const float4*)(gx + 4);
                const float* gw = W + (size_t)(n0 + srow[r]) * DMODEL + k0 + scol[r] * 8;
                wr[s][r][0] = *(const float4*)gw;
                wr[s][r][1] = *(const float4*)(gw + 4);
            }
        }

        #pragma unroll
        for (int ks = 0; ks < 2; ++ks) {
            bf16x8 af[2], bfr[2];
            #pragma unroll
            for (int i = 0; i < 2; ++i) {
                const int ch = (((ks << 2) | quad) ^ swz) * 8;
                af[i]  = *(const bf16x8*)&Xs[(wm + i * 16 + l16) * 64 + ch];
                bfr[i] = *(const bf16x8*)&Ws[(wn + i * 16 + l16) * 64 + ch];
            }
            #pragma unroll
            for (int i = 0; i < 2; ++i)
                #pragma unroll
                for (int j = 0; j < 2; ++j)
                    acc[i][j] = __builtin_amdgcn_mfma_f32_16x16x32_bf16(
                        af[i], bfr[j], acc[i][j], 0, 0, 0);
        }
    }

    #pragma unroll
    for (int i = 0; i < 2; ++i) {
        #pragma unroll
        for (int j = 0; j < 2; ++j) {
            const int gn = n0 + wn + j * 16 + l16;
            const float bv = bias[gn];
            #pragma unroll
            for (int r = 0; r < 4; ++r) {
                const int gm = m0 + wm + i * 16 + quad * 4 + r;
                float v = acc[i][j][r] + bv;
                v = v > 0.f ? v : 0.f;
                H[(size_t)gm * DPROJ + gn] = (bf16_t)v;
            }
        }
    }
}

// ---------------------------------------------------------------------------
// Kernel 2 v2: Out[b,i,j] = scale * sum_p H[b,i,p]*H[b,j,p] + off.
//
// REDESIGN: LDS-free, barrier-free, direct-from-L2 fragment GEMM.
//   - H is 1 MB/batch (4 MB total) -> fully L2-resident; LDS staging and the
//     old 4x {barrier, global_load_lds, vmcnt(0)-drain barrier} chain were the
//     bottleneck (latency-serialized, ~8 MFMA of work per ~500-cycle wait).
//   - 128x128 TRIANGULAR tiles: 136/batch, 544 blocks, 4 waves/block.
//   - Each wave owns a 64x64 quadrant: 4x4 fragments (64 acc VGPR),
//     read:MFMA = 0.5 (vs 1.0 at 2x2) -> halves L2 operand traffic.
//   - A/B fragments loaded straight from global with global_load_dwordx4:
//     per instr = 16 rows x 64 B contiguous, an ideal L2 pattern.
//   - Full K=256 unrolled (8 k-steps x 16 MFMA), zero __syncthreads.
//   - Kernel should be bound by the 67 MB Out store stream (~11 us floor).
// Fragment layout (mfma_f32_16x16x32_bf16, verified m89):
//   A/B in: row/col = l16, k = quad*8 + [0..8);  C out: col = l16,
//   row = quad*4 + reg.
// ---------------------------------------------------------------------------
__global__ __launch_bounds__(256, 2) void score_kernel(
    const bf16_t* __restrict__ H, const float* __restrict__ clf_w,
    const float* __restrict__ clf_b, float* __restrict__ Out)
{
    // triangular decode: blockIdx.x in [0,136) -> (bi,bj), bi<=bj, T=16
    int t = blockIdx.x, bi = 0, rl = SEQ / 128;
    while (t >= rl) { t -= rl; --rl; ++bi; }
    const int bj = bi + t;
    const int b  = blockIdx.y;
    const int m0 = bi * 128;
    const int n0 = bj * 128;
    const bf16_t* Hb = H + (size_t)b * SEQ * DPROJ;
    float* Ob = Out + (size_t)b * SEQ * SEQ;

    const int tid  = threadIdx.x;
    const int lane = tid & 63;
    const int wave = tid >> 6;
    const int quad = lane >> 4;
    const int l16  = lane & 15;
    const int wm = (wave & 1) * 64;    // 2x2 wave grid, 64x64 per wave
    const int wn = (wave >> 1) * 64;

    // per-lane fragment base pointers (16B-aligned: row*512B + quad*16B)
    const bf16_t* pa = Hb + (size_t)(m0 + wm + l16) * DPROJ + quad * 8;
    const bf16_t* pb = Hb + (size_t)(n0 + wn + l16) * DPROJ + quad * 8;

    f32x4 acc[4][4] = {};

    #pragma unroll
    for (int ks = 0; ks < 8; ++ks) {
        bf16x8 af[4], bfr[4];
        #pragma unroll
        for (int i = 0; i < 4; ++i) {
            af[i]  = *(const bf16x8*)(pa + (size_t)(i * 16) * DPROJ + ks * 32);
            bfr[i] = *(const bf16x8*)(pb + (size_t)(i * 16) * DPROJ + ks * 32);
        }
        #pragma unroll
        for (int i = 0; i < 4; ++i)
            #pragma unroll
            for (int j = 0; j < 4; ++j)
                acc[i][j] = __builtin_amdgcn_mfma_f32_16x16x32_bf16(
                    af[i], bfr[j], acc[i][j], 0, 0, 0);
    }

    const float scale = clf_w[0];
    const float off   = clf_b[0];

    // direct tile (bi,bj): per instr 4 rows (quad) x 16 consecutive cols (l16)
    #pragma unroll
    for (int i = 0; i < 4; ++i) {
        #pragma unroll
        for (int r = 0; r < 4; ++r) {
            const int gm = m0 + wm + i * 16 + quad * 4 + r;
            float* row = Ob + (size_t)gm * SEQ + n0 + wn + l16;
            #pragma unroll
            for (int j = 0; j < 4; ++j)
                row[j * 16] = acc[i][j][r] * scale + off;
        }
    }

    // mirror tile (bj,bi): row gn, 4 consecutive cols gm -> float4 store
    if (bi != bj) {
        #pragma unroll
        for (int j = 0; j < 4; ++j) {
            const int gn = n0 + wn + j * 16 + l16;
            float* row = Ob + (size_t)gn * SEQ + m0 + wm + quad * 4;
            #pragma unroll
            for (int i = 0; i < 4; ++i) {
                float4 v;
                v.x = acc[i][j][0] * scale + off;
                v.y = acc[i][j][1] * scale + off;
                v.z = acc[i][j][2] * scale + off;
                v.w = acc[i][j][3] * scale + off;
                *(float4*)(row + i * 16) = v;
            }
        }
    }
}

extern "C" void kernel_launch(void* const* d_in, const int* in_sizes, int n_in,
                              void* d_out, int out_size, void* d_ws, size_t ws_size,
                              hipStream_t stream) {
    const float* X    = (const float*)d_in[0];  // [4,2048,1024]
    const float* W    = (const float*)d_in[1];  // [256,1024]
    const float* bias = (const float*)d_in[2];  // [256]
    const float* clfw = (const float*)d_in[3];  // [1,1]
    const float* clfb = (const float*)d_in[4];  // [1]
    float* Out = (float*)d_out;                 // [4,2048,2048]
    bf16_t* H  = (bf16_t*)d_ws;                 // [8192,256] bf16 = 4 MB

    dim3 g1(NBATCH * SEQ / 64, DPROJ / 64, 1);  // 128 x 4 = 512 blocks
    proj_kernel<<<g1, 256, 0, stream>>>(X, W, bias, H);

    const int ntile = SEQ / 128;                // 16
    dim3 g2(ntile * (ntile + 1) / 2, NBATCH);   // 136 x 4 = 544 blocks
    score_kernel<<<g2, 256, 0, stream>>>(H, clfw, clfb, Out);
}